// Round 1
// baseline (881.864 us; speedup 1.0000x reference)
//
#include <hip/hip_runtime.h>
#include <math.h>

// Problem constants (N=2, C=64, H=96, W=96, PATCH=3)
static constexpr int NITEM = 2;
static constexpr int C = 64;
static constexpr int H = 96;
static constexpr int W = 96;
static constexpr int HW = H * W;        // 9216
static constexpr int HP = 94;           // H - 3 + 1
static constexpr int NP = HP * HP;      // 8836
static constexpr int NDY = 2 * HP - 1;  // 187 displacement rows (Δy = -93..93)
static constexpr int MAXQ = 4;          // max y-pieces per Δy (load balance)

// Order-preserving fp32 -> uint32 (v1 > v2  <=>  key(v1) > key(v2))
__device__ __forceinline__ unsigned int fkey(float v) {
    unsigned int u = __float_as_uint(v);
    return (u & 0x80000000u) ? ~u : (u | 0x80000000u);
}

__device__ __forceinline__ unsigned long long shflx64(unsigned long long v, int m) {
    int lo = __shfl_xor((int)(unsigned int)v, m);
    int hi = __shfl_xor((int)(unsigned int)(v >> 32), m);
    return ((unsigned long long)(unsigned int)hi << 32) | (unsigned int)lo;
}

// ---------------- Kernel 1: per-pixel channel L2 normalize + NCHW->NHWC ----------------
__global__ __launch_bounds__(256) void normalize_kernel(
    const float* __restrict__ f1, const float* __restrict__ f2,
    float* __restrict__ fiN, float* __restrict__ frN, float* __restrict__ ssn)
{
    int t = blockIdx.x * 256 + threadIdx.x;
    const int perTensor = NITEM * HW;
    if (t >= 2 * perTensor) return;
    int which = t / perTensor;
    int p = t - which * perTensor;
    int n = p / HW;
    int pix = p - n * HW;
    const float* src = (which ? f2 : f1) + (size_t)n * C * HW + pix;
    float s = 0.f;
    #pragma unroll
    for (int c = 0; c < C; c++) {
        float v = src[c * HW];
        s = fmaf(v, v, s);
    }
    float norm = sqrtf(s);
    float scale = 1.0f / fmaxf(norm, 1e-12f);
    float* dst = (which ? frN : fiN) + (size_t)p * C;
    #pragma unroll
    for (int c = 0; c < C; c++) {
        dst[c] = src[c * HW] * scale;
    }
    if (which) ssn[p] = s * scale * scale;
}

// ---------------- Kernel 2: ref patch inverse norms ----------------
__global__ __launch_bounds__(256) void refnorm_kernel(
    const float* __restrict__ ssn, float* __restrict__ invn)
{
    int t = blockIdx.x * 256 + threadIdx.x;
    if (t >= NITEM * NP) return;
    int n = t / NP;
    int r = t - n * NP;
    int yr = r / HP, xr = r - yr * HP;
    const float* s = ssn + n * HW;
    float acc = 0.f;
    #pragma unroll
    for (int dy = 0; dy < 3; dy++)
        #pragma unroll
        for (int dx = 0; dx < 3; dx++)
            acc += s[(yr + dy) * W + (xr + dx)];
    invn[t] = 1.0f / (sqrtf(acc) + 1e-5f);
}

// ---------------- Kernel 3: fused diagonal cost-volume + argmax ----------------
// Block = (Δy index d, y-piece h, item n).  For each pixel-row y we compute the
// row-pair GEMM  G[u][v] = sum_c fi[y,u,c] * fr[y+dy,v,c]  (96x96x64) into LDS,
// then the 3-tap diagonal sums B_y[xi][xr] = G[xi][xr]+G[xi+1][xr+1]+G[xi+2][xr+2].
// corr(yi) = B_yi + B_{yi+1} + B_{yi+2} is assembled in thread-private register
// planes (pA = two-term partial, pB = one-term partial) and finalized (x invn,
// argmax over xr, packed-u64 atomicMax into best[i]) when its third term lands.
// Association matches the old gemmP+pass2 exactly: ascending-c fmaf chain for G,
// (g0+g1)+g2 over dx, ((B0+B1)+B2) over dy  ->  bit-identical correlation values.
__global__ __launch_bounds__(256, 1) void corr_diag_kernel(
    const float* __restrict__ fiN, const float* __restrict__ frN,
    const float* __restrict__ invn, unsigned long long* __restrict__ best)
{
    // 88,576 B LDS -> 1 block/CU; VGPR budget is 512/wave at this occupancy.
    __shared__ struct {
        float2 Ap[32][98];   // fi row, channel-pair major: [c2][x] = {c=2c2, c=2c2+1}
        float2 Bp[32][98];   // fr row, same layout (98 pad breaks staging-write conflicts)
        float  G[96][100];   // G[u][v]; stride 100 floats = 400 B (16B-aligned rows)
    } sm;

    const int t = threadIdx.x;
    const int d = blockIdx.x;
    const int h = blockIdx.y;
    const int n = blockIdx.z;
    const int dy = d - (HP - 1);             // Δy = yr - yi
    const int ady = dy < 0 ? -dy : dy;
    const int nyi = HP - ady;                // valid yi count for this Δy

    int q = 1 + (nyi - 1) / 24; if (q > MAXQ) q = MAXQ;
    if (h >= q) return;
    const int L = (nyi + q - 1) / q;
    const int yi0 = dy < 0 ? -dy : 0;
    const int ya = yi0 + h * L;
    int nb = nyi - h * L; if (nb > L) nb = L;
    if (nb <= 0) return;
    const int yb = ya + nb;                  // finalize yi in [ya, yb)

    const float* fa = fiN + (size_t)n * HW * C;
    const float* fb = frN + (size_t)n * HW * C;
    const float* inv = invn + (size_t)n * NP;
    unsigned long long* bn = best + (size_t)n * NP;

    // phase-1 (GEMM) frag coords: 16x16 grid, 6x6 frag
    const int tu = t & 15;                   // u base = 6*tu
    const int tv = t >> 4;                   // v base = 6*tv
    // phase-2 (taps) coords: 8 xr-strips of 12, xi = xib + 32p
    const int s  = t & 7;
    const int xib = t >> 3;

    float pA[3][12], pB[3][12];              // pending corr partials (regs)
    float4 nx[12];                           // next-row staging regs (T14 split)

    // ---- prologue: stage rows (ya, ya+dy) ----
    {
        const float* pfa = fa + (size_t)ya * W * C;
        const float* pfb = fb + (size_t)(ya + dy) * W * C;
        #pragma unroll
        for (int j = 0; j < 6; j++) {
            int id = t + 256 * j;            // 1536 tasks: u = id>>4, cq = id&15
            int u = id >> 4, cq = id & 15;
            float4 va = *(const float4*)(pfa + u * C + cq * 4);
            float4 vb = *(const float4*)(pfb + u * C + cq * 4);
            sm.Ap[2 * cq    ][u] = make_float2(va.x, va.y);
            sm.Ap[2 * cq + 1][u] = make_float2(va.z, va.w);
            sm.Bp[2 * cq    ][u] = make_float2(vb.x, vb.y);
            sm.Bp[2 * cq + 1][u] = make_float2(vb.z, vb.w);
        }
    }
    __syncthreads();

    for (int y = ya; y <= yb + 1; ++y) {
        const bool notLast = (y < yb + 1);
        const bool doFin = (y >= ya + 2);    // finalize yi = y-2
        const bool doA = (y > ya);           // promote pB -> pA
        const int yi = y - 2;
        const int yr = yi + dy;

        // issue next-row global loads early; LDS-write happens after phase 2
        if (notLast) {
            const float* pfa = fa + (size_t)(y + 1) * W * C;
            const float* pfb = fb + (size_t)(y + 1 + dy) * W * C;
            #pragma unroll
            for (int j = 0; j < 6; j++) {
                int id = t + 256 * j;
                nx[j]     = *(const float4*)(pfa + (id >> 4) * C + (id & 15) * 4);
                nx[6 + j] = *(const float4*)(pfb + (id >> 4) * C + (id & 15) * 4);
            }
        }
        float invr[12];
        if (doFin) {
            const float* ivp = inv + yr * HP + 12 * s;   // OOB lanes masked at compare
            #pragma unroll
            for (int j = 0; j < 12; j++) invr[j] = ivp[j];
        }

        // ---- phase 1: G = fiRow x frRow^T (96x96, K=64, k-pair packed) ----
        float acc[6][6];
        #pragma unroll
        for (int i = 0; i < 6; i++)
            #pragma unroll
            for (int j = 0; j < 6; j++) acc[i][j] = 0.f;

        #pragma unroll 4
        for (int kp = 0; kp < 32; kp++) {
            const float4* ap = (const float4*)(&sm.Ap[kp][6 * tu]);  // 16B-aligned: 784*kp+48*tu
            const float4* bp = (const float4*)(&sm.Bp[kp][6 * tv]);
            float4 A0 = ap[0], A1 = ap[1], A2 = ap[2];
            float4 B0 = bp[0], B1 = bp[1], B2 = bp[2];
            float ae[6] = {A0.x, A0.z, A1.x, A1.z, A2.x, A2.z};      // channel 2kp
            float ao[6] = {A0.y, A0.w, A1.y, A1.w, A2.y, A2.w};      // channel 2kp+1
            float be[6] = {B0.x, B0.z, B1.x, B1.z, B2.x, B2.z};
            float bo[6] = {B0.y, B0.w, B1.y, B1.w, B2.y, B2.w};
            #pragma unroll
            for (int i = 0; i < 6; i++)
                #pragma unroll
                for (int j = 0; j < 6; j++) {
                    acc[i][j] = fmaf(ae[i], be[j], acc[i][j]);       // even k first:
                    acc[i][j] = fmaf(ao[i], bo[j], acc[i][j]);       // ascending-c chain
                }
        }
        #pragma unroll
        for (int i = 0; i < 6; i++) {
            float2* gw = (float2*)(&sm.G[6 * tu + i][6 * tv]);
            gw[0] = make_float2(acc[i][0], acc[i][1]);
            gw[1] = make_float2(acc[i][2], acc[i][3]);
            gw[2] = make_float2(acc[i][4], acc[i][5]);
        }
        __syncthreads();

        // ---- phase 2: diagonal taps, pend rotate, finalize yi = y-2 ----
        #pragma unroll
        for (int p = 0; p < 3; p++) {
            const int xi = 32 * p + xib;
            if (xi < HP) {
                float w0[16], w1[16], w2[16];
                const float4* g0 = (const float4*)(&sm.G[xi    ][12 * s]); // 16-float window,
                const float4* g1 = (const float4*)(&sm.G[xi + 1][12 * s]); // max col 99 -> fits
                const float4* g2 = (const float4*)(&sm.G[xi + 2][12 * s]); // stride 100 exactly
                #pragma unroll
                for (int qq = 0; qq < 4; qq++) {
                    float4 a = g0[qq]; w0[4*qq]=a.x; w0[4*qq+1]=a.y; w0[4*qq+2]=a.z; w0[4*qq+3]=a.w;
                    float4 b = g1[qq]; w1[4*qq]=b.x; w1[4*qq+1]=b.y; w1[4*qq+2]=b.z; w1[4*qq+3]=b.w;
                    float4 c = g2[qq]; w2[4*qq]=c.x; w2[4*qq+1]=c.y; w2[4*qq+2]=c.z; w2[4*qq+3]=c.w;
                }
                float Bv[12];
                #pragma unroll
                for (int j = 0; j < 12; j++)
                    Bv[j] = (w0[j] + w1[j + 1]) + w2[j + 2];          // (g0+g1)+g2, as pass2

                if (doFin) {
                    float bv = -INFINITY; int brx = 0;
                    #pragma unroll
                    for (int j = 0; j < 12; j++) {
                        float v = (pA[p][j] + Bv[j]) * invr[j];       // ((B0+B1)+B2)*inv
                        if ((12 * s + j) < HP && v > bv) { bv = v; brx = 12 * s + j; }
                    }
                    unsigned long long key =
                        ((unsigned long long)fkey(bv) << 32)
                        | (unsigned int)(~(unsigned int)(yr * HP + brx));
                    #pragma unroll
                    for (int m = 1; m < 8; m <<= 1) {                 // reduce 8 xr-strips
                        unsigned long long o = shflx64(key, m);
                        if (o > key) key = o;
                    }
                    if (s == 0) atomicMax(&bn[yi * HP + xi], key);
                }
                if (doA) {
                    #pragma unroll
                    for (int j = 0; j < 12; j++) pA[p][j] = pB[p][j] + Bv[j];
                }
                #pragma unroll
                for (int j = 0; j < 12; j++) pB[p][j] = Bv[j];
            }
        }
        // write staged next rows into panels (panels are only read in phase 1)
        if (notLast) {
            #pragma unroll
            for (int j = 0; j < 6; j++) {
                int id = t + 256 * j;
                int u = id >> 4, cq = id & 15;
                sm.Ap[2 * cq    ][u] = make_float2(nx[j].x, nx[j].y);
                sm.Ap[2 * cq + 1][u] = make_float2(nx[j].z, nx[j].w);
                sm.Bp[2 * cq    ][u] = make_float2(nx[6 + j].x, nx[6 + j].y);
                sm.Bp[2 * cq + 1][u] = make_float2(nx[6 + j].z, nx[6 + j].w);
            }
        }
        __syncthreads();
    }
}

// ---------------- Kernel 4: expand to 9 shifted copies, channel-interleaved ----------------
__global__ __launch_bounds__(256) void expand_best_kernel(
    const unsigned long long* __restrict__ best, float* __restrict__ out)
{
    int t = blockIdx.x * 256 + threadIdx.x;
    const int total = NITEM * 18 * HW;
    if (t >= total) return;
    int x = t % W;
    int y = (t / W) % H;
    int chn = (t / HW) % 18;
    int n = t / (18 * HW);
    int k = chn >> 1;
    int b = chn & 1;          // 0 -> flow_h, 1 -> flow_w
    int is = k / 3, js = k - is * 3;
    int ys = y - is, xs = x - js;
    float val = 0.f;
    if (ys >= 0 && ys < HP && xs >= 0 && xs < HP) {
        int i = ys * HP + xs;
        unsigned long long key = best[(size_t)n * NP + i];
        int idx = (int)(~(unsigned int)key);
        int yr = idx / HP, xr = idx - yr * HP;
        val = b ? (float)(xr - xs) : (float)(yr - ys);
    }
    out[t] = val;
}

// ---------------- Launch ----------------
extern "C" void kernel_launch(void* const* d_in, const int* in_sizes, int n_in,
                              void* d_out, int out_size, void* d_ws, size_t ws_size,
                              hipStream_t stream) {
    (void)in_sizes; (void)n_in; (void)out_size; (void)ws_size;
    const float* f1 = (const float*)d_in[0];
    const float* f2 = (const float*)d_in[1];
    float* ws = (float*)d_ws;

    float* fiN  = ws;                                   // 2*9216*64
    float* frN  = fiN + (size_t)NITEM * HW * C;         // 2*9216*64
    float* ssn  = frN + (size_t)NITEM * HW * C;         // 2*9216
    float* invn = ssn + (size_t)NITEM * HW;             // 2*8836
    unsigned long long* best =
        (unsigned long long*)((((uintptr_t)(invn + (size_t)NITEM * NP)) + 15) & ~(uintptr_t)15);
    // total ~9.7 MB — far below previous 184 MB slab requirement

    normalize_kernel<<<(2 * NITEM * HW + 255) / 256, 256, 0, stream>>>(f1, f2, fiN, frN, ssn);
    refnorm_kernel<<<(NITEM * NP + 255) / 256, 256, 0, stream>>>(ssn, invn);
    hipMemsetAsync(best, 0, (size_t)NITEM * NP * sizeof(unsigned long long), stream);
    corr_diag_kernel<<<dim3(NDY, MAXQ, NITEM), 256, 0, stream>>>(fiN, frN, invn, best);
    expand_best_kernel<<<(NITEM * 18 * HW + 255) / 256, 256, 0, stream>>>(best, (float*)d_out);
}